// Round 15
// baseline (411.943 us; speedup 1.0000x reference)
//
#include <hip/hip_runtime.h>
#include <hip/hip_bf16.h>
#include <hip/hip_fp16.h>
#include <hip/hip_cooperative_groups.h>

// GraphSAGE(2-layer, mean agg) + 3-layer MLP link predictor.
// N=100000, E=1.6M, E_PAIR=100000, D=128.
// Round 15: single cooperative kernel for setup+CSR build (cvt/hist -> scan ->
// partition -> rowoff+scatter with grid.sync between phases). 11 -> 7 launches.

namespace cg = cooperative_groups;

#define D 128
#define NR 512
#define EMAX 4608
#define LDA 40       // f16 elems per staged row (80B stride: 2-way banks = free)
#define LDAGG 136    // s_h2 row stride f16
#define LDH2 136     // s_h1 row stride f16

typedef _Float16 f16x8 __attribute__((ext_vector_type(8)));
typedef float f32x4 __attribute__((ext_vector_type(4)));

__device__ __forceinline__ void cvt8(const float* src, _Float16* dst, int off8) {
    const float4* s4 = (const float4*)src;
    float4 a = s4[2 * off8], b = s4[2 * off8 + 1];
    f16x8 h;
    h[0] = (_Float16)a.x; h[1] = (_Float16)a.y; h[2] = (_Float16)a.z; h[3] = (_Float16)a.w;
    h[4] = (_Float16)b.x; h[5] = (_Float16)b.y; h[6] = (_Float16)b.z; h[7] = (_Float16)b.w;
    *(f16x8*)(dst + 8 * off8) = h;
}

// ---------------- cooperative setup + CSR build ----------------
// grid = 512 blocks x 256 threads (co-resident: ~29KB LDS -> >=2 blocks/CU).
__global__ __launch_bounds__(256) void k_csr(
    const float* __restrict__ x, _Float16* __restrict__ xf, int n8,
    const float* __restrict__ W1s, const float* __restrict__ W1n,
    const float* __restrict__ W2s, const float* __restrict__ W2n,
    const float* __restrict__ P1w, const float* __restrict__ P2w,
    _Float16* __restrict__ Ws1f, _Float16* __restrict__ Wn1f,
    _Float16* __restrict__ Ws2f, _Float16* __restrict__ Wn2f,
    _Float16* __restrict__ P1cf, _Float16* __restrict__ P2wf,
    const int* __restrict__ esrc, const int* __restrict__ edst,
    unsigned int* __restrict__ epart, int* __restrict__ csr,
    int* __restrict__ row_off, int* __restrict__ region_cnt,
    int* __restrict__ cursor2, int n, int e, int bound) {
    cg::grid_group grid = cg::this_grid();
    __shared__ int s_h[NR];        // phase0 hist / phase2 counts
    __shared__ int s_base[NR];     // exclusive region base (persists)
    __shared__ int s_cntA[NR];     // region counts (persists)
    __shared__ int s_resv[NR];     // phase2 reservations
    __shared__ unsigned int s_e[EMAX];
    __shared__ int s_deg[256];
    __shared__ int s_scan[256];
    __shared__ int s_cur[256];
    int tid = threadIdx.x;
    int bid = blockIdx.x;
    int gstride = gridDim.x * 256;
    int gtid = bid * 256 + tid;

    // ---- phase 0: cvt x, cvt weights, edge histogram ----
    for (int i = gtid; i < n8; i += gstride) cvt8(x, xf, i);
    for (int g = gtid; g < 14336; g += gstride) {
        if (g >= 8192 && g < 12288) {
            int u = g - 8192;
            int o = u >> 4, col = (u & 15) * 8;
            const float* src = P1w + (size_t)(o & 127) * 256 + ((o >> 7) * 128) + col;
            float4 a = *(const float4*)src, bb = *(const float4*)(src + 4);
            f16x8 h;
            h[0] = (_Float16)a.x; h[1] = (_Float16)a.y; h[2] = (_Float16)a.z; h[3] = (_Float16)a.w;
            h[4] = (_Float16)bb.x; h[5] = (_Float16)bb.y; h[6] = (_Float16)bb.z; h[7] = (_Float16)bb.w;
            *(f16x8*)(P1cf + (size_t)u * 8) = h;
        } else {
            const float* src; _Float16* dstp; int off;
            if      (g <  2048) { src = W1s; dstp = Ws1f; off = g; }
            else if (g <  4096) { src = W1n; dstp = Wn1f; off = g - 2048; }
            else if (g <  6144) { src = W2s; dstp = Ws2f; off = g - 4096; }
            else if (g <  8192) { src = W2n; dstp = Wn2f; off = g - 6144; }
            else                { src = P2w; dstp = P2wf; off = g - 12288; }
            cvt8(src, dstp, off);
        }
    }
    for (int i = tid; i < NR; i += 256) s_h[i] = 0;
    __syncthreads();
    for (int i = gtid; i < e; i += gstride)
        atomicAdd(&s_h[edst[i] / bound], 1);
    __syncthreads();
    for (int i = tid; i < NR; i += 256)
        if (s_h[i]) atomicAdd(&region_cnt[i], s_h[i]);

    grid.sync();

    // ---- phase 1: every block scans region counts (512 elems, 256 thr) ----
    {
        int c0 = region_cnt[tid], c1 = region_cnt[tid + 256];
        s_cntA[tid] = c0; s_cntA[tid + 256] = c1;
        s_base[tid] = c0; s_base[tid + 256] = c1;   // will become inclusive
        __syncthreads();
        #pragma unroll
        for (int off = 1; off < NR; off <<= 1) {
            int t2 = tid + 256;
            int v0 = (tid >= off) ? s_base[tid - off] : 0;
            int v1 = (t2 >= off) ? s_base[t2 - off] : 0;
            __syncthreads();
            s_base[tid] += v0; s_base[t2] += v1;
            __syncthreads();
        }
        // inclusive -> exclusive
        int e0 = s_base[tid] - s_cntA[tid];
        int e1 = s_base[tid + 256] - s_cntA[tid + 256];
        __syncthreads();
        s_base[tid] = e0; s_base[tid + 256] = e1;
        __syncthreads();
    }

    // ---- phase 2: partition own span into epart (region-compacted) ----
    {
        int per = (e + gridDim.x - 1) / gridDim.x;
        int beg = bid * per, end = min(beg + per, e);
        for (int i = tid; i < NR; i += 256) s_h[i] = 0;
        __syncthreads();
        for (int i = beg + tid; i < end; i += 256)
            atomicAdd(&s_h[edst[i] / bound], 1);
        __syncthreads();
        for (int i = tid; i < NR; i += 256)
            s_resv[i] = s_base[i] + (s_h[i] ? atomicAdd(&cursor2[i], s_h[i]) : 0);
        __syncthreads();
        for (int i = tid; i < NR; i += 256) s_h[i] = 0;
        __syncthreads();
        for (int i = beg + tid; i < end; i += 256) {
            int d = edst[i];
            int r = d / bound;
            unsigned int doff = (unsigned int)(d - r * bound);
            int p = atomicAdd(&s_h[r], 1);
            epart[s_resv[r] + p] = (unsigned int)esrc[i] | (doff << 20);
        }
    }

    grid.sync();

    // ---- phase 3: block r = region r: rowoff + scatter ----
    {
        int r = bid;
        int rlo = r * bound;
        if (tid == 0 && r == 0) row_off[n] = s_base[NR - 1] + s_cntA[NR - 1];
        if (rlo >= n) return;
        int nn = min(bound, n - rlo);
        int beg = s_base[r];
        int cnt = s_cntA[r];
        bool fit = (cnt <= EMAX);
        if (fit)
            for (int i = tid; i < cnt; i += 256) s_e[i] = epart[beg + i];
        s_deg[tid] = 0;
        __syncthreads();
        for (int i = tid; i < cnt; i += 256)
            atomicAdd(&s_deg[(fit ? s_e[i] : epart[beg + i]) >> 20], 1);
        __syncthreads();
        int v = (tid < nn) ? s_deg[tid] : 0;
        s_scan[tid] = v;
        __syncthreads();
        #pragma unroll
        for (int off = 1; off < 256; off <<= 1) {
            int add = (tid >= off) ? s_scan[tid - off] : 0;
            __syncthreads();
            s_scan[tid] += add;
            __syncthreads();
        }
        int base = beg + (tid ? s_scan[tid - 1] : 0);
        s_cur[tid] = base;
        if (tid < nn) row_off[rlo + tid] = base;
        __syncthreads();
        for (int i = tid; i < cnt; i += 256) {
            unsigned int e2 = fit ? s_e[i] : epart[beg + i];
            int doff = e2 >> 20;
            int p = atomicAdd(&s_cur[doff], 1);
            csr[p] = e2 & 0xFFFFF;
        }
    }
}

// ---------------- mean aggregation: 16-lane group per node ----------------
__global__ __launch_bounds__(256) void k_agg(
    const _Float16* __restrict__ Xf, const int* __restrict__ row_off,
    const int* __restrict__ csr, _Float16* __restrict__ Aggf, int n_nodes) {
    int g = blockIdx.x * 16 + (threadIdx.x >> 4);
    if (g >= n_nodes) return;
    int l = threadIdx.x & 15;
    int beg = row_off[g], end = row_off[g + 1];
    float acc[8] = {0.f, 0.f, 0.f, 0.f, 0.f, 0.f, 0.f, 0.f};
    int i = beg;
    for (; i + 8 <= end; i += 8) {
        int si[8];
        #pragma unroll
        for (int j = 0; j < 8; ++j) si[j] = csr[i + j];
        f16x8 vv[8];
        #pragma unroll
        for (int j = 0; j < 8; ++j)
            vv[j] = *(const f16x8*)(Xf + (size_t)si[j] * D + l * 8);
        #pragma unroll
        for (int j = 0; j < 8; ++j)
            #pragma unroll
            for (int k = 0; k < 8; ++k) acc[k] += (float)vv[j][k];
    }
    for (; i + 2 <= end; i += 2) {
        int s0 = csr[i], s1 = csr[i + 1];
        f16x8 v0 = *(const f16x8*)(Xf + (size_t)s0 * D + l * 8);
        f16x8 v1 = *(const f16x8*)(Xf + (size_t)s1 * D + l * 8);
        #pragma unroll
        for (int k = 0; k < 8; ++k) acc[k] += (float)v0[k] + (float)v1[k];
    }
    if (i < end) {
        int s0 = csr[i];
        f16x8 v0 = *(const f16x8*)(Xf + (size_t)s0 * D + l * 8);
        #pragma unroll
        for (int k = 0; k < 8; ++k) acc[k] += (float)v0[k];
    }
    float inv = 1.0f / fmaxf((float)(end - beg), 1.0f);
    f16x8 o;
    #pragma unroll
    for (int k = 0; k < 8; ++k) o[k] = (_Float16)(acc[k] * inv);
    *(f16x8*)(Aggf + (size_t)g * D + l * 8) = o;
}

// ---------------- layer-1 transform (MFMA, double-buffered, relu) ----------------
__global__ __launch_bounds__(512) void k_transform(
    const _Float16* __restrict__ Xf, const _Float16* __restrict__ Aggf,
    const _Float16* __restrict__ Wsf, const _Float16* __restrict__ Wnf,
    const float* __restrict__ bias, _Float16* __restrict__ outf, int n_rows) {
    __shared__ _Float16 s_a[2][128 * LDA];
    __shared__ _Float16 s_b[2][128 * LDA];
    int tid = threadIdx.x;
    int w = tid >> 6, l = tid & 63;
    int wr = w >> 1, wc = w & 1;
    int l15 = l & 15, lk = l >> 4;
    int n0 = blockIdx.x * 128;
    int r = tid >> 2, q = tid & 3;
    int rstage = n0 + r; if (rstage >= n_rows) rstage = n_rows - 1;

    f32x4 acc[2][4];
    #pragma unroll
    for (int i = 0; i < 2; ++i)
        #pragma unroll
        for (int j = 0; j < 4; ++j) acc[i][j] = (f32x4){0.f, 0.f, 0.f, 0.f};

    int a_off = (wr * 32 + l15) * LDA + lk * 8;
    int b_off = (wc * 64 + l15) * LDA + lk * 8;
    int st_off = r * LDA + q * 8;

    {
        f16x8 av = *(const f16x8*)(Xf + (size_t)rstage * D + q * 8);
        f16x8 wv = *(const f16x8*)(Wsf + (size_t)r * D + q * 8);
        *(f16x8*)(&s_a[0][st_off]) = av;
        *(f16x8*)(&s_b[0][st_off]) = wv;
    }
    __syncthreads();

    for (int c = 0; c < 8; ++c) {
        int b = c & 1;
        f16x8 av, wv;
        if (c < 7) {
            int cn = c + 1;
            const _Float16* asrc = (cn < 4) ? Xf : Aggf;
            const _Float16* wsrc = (cn < 4) ? Wsf : Wnf;
            int kb = (cn & 3) * 32;
            av = *(const f16x8*)(asrc + (size_t)rstage * D + kb + q * 8);
            wv = *(const f16x8*)(wsrc + (size_t)r * D + kb + q * 8);
        }
        f16x8 af[2], bf[4];
        af[0] = *(const f16x8*)(&s_a[b][a_off]);
        af[1] = *(const f16x8*)(&s_a[b][a_off + 16 * LDA]);
        #pragma unroll
        for (int j = 0; j < 4; ++j) bf[j] = *(const f16x8*)(&s_b[b][b_off + j * 16 * LDA]);
        #pragma unroll
        for (int i = 0; i < 2; ++i)
            #pragma unroll
            for (int j = 0; j < 4; ++j)
                acc[i][j] = __builtin_amdgcn_mfma_f32_16x16x32_f16(af[i], bf[j], acc[i][j], 0, 0, 0);
        if (c < 7) {
            *(f16x8*)(&s_a[b ^ 1][st_off]) = av;
            *(f16x8*)(&s_b[b ^ 1][st_off]) = wv;
        }
        __syncthreads();
    }

    #pragma unroll
    for (int j = 0; j < 4; ++j) {
        int col = wc * 64 + j * 16 + l15;
        float bv = bias[col];
        #pragma unroll
        for (int i = 0; i < 2; ++i) {
            int rowb = n0 + wr * 32 + i * 16 + lk * 4;
            #pragma unroll
            for (int v = 0; v < 4; ++v) {
                int row = rowb + v;
                if (row < n_rows)
                    outf[(size_t)row * D + col] = (_Float16)fmaxf(acc[i][j][v] + bv, 0.f);
            }
        }
    }
}

// ---------------- layer-2 transform fused with Pre GEMM ----------------
__global__ __launch_bounds__(512) void k_transform_pre(
    const _Float16* __restrict__ Xf, const _Float16* __restrict__ Aggf,
    const _Float16* __restrict__ Wsf, const _Float16* __restrict__ Wnf,
    const float* __restrict__ bias, const _Float16* __restrict__ P1cf,
    _Float16* __restrict__ Pre, int n_rows) {
    __shared__ _Float16 s_a[2][128 * LDA];
    __shared__ _Float16 s_b[2][128 * LDA];
    __shared__ _Float16 s_h2[128 * LDAGG];
    int tid = threadIdx.x;
    int w = tid >> 6, l = tid & 63;
    int l15 = l & 15, lk = l >> 4;
    int n0 = blockIdx.x * 128;
    int r = tid >> 2, q = tid & 3;
    int rstage = n0 + r; if (rstage >= n_rows) rstage = n_rows - 1;

    {
        int wr = w >> 1, wc = w & 1;
        f32x4 acc[2][4];
        #pragma unroll
        for (int i = 0; i < 2; ++i)
            #pragma unroll
            for (int j = 0; j < 4; ++j) acc[i][j] = (f32x4){0.f, 0.f, 0.f, 0.f};

        int a_off = (wr * 32 + l15) * LDA + lk * 8;
        int b_off = (wc * 64 + l15) * LDA + lk * 8;
        int st_off = r * LDA + q * 8;

        f16x8 av0 = *(const f16x8*)(Xf + (size_t)rstage * D + q * 8);
        f16x8 wv0 = *(const f16x8*)(Wsf + (size_t)r * D + q * 8);
        *(f16x8*)(&s_a[0][st_off]) = av0;
        *(f16x8*)(&s_b[0][st_off]) = wv0;
        __syncthreads();

        for (int c = 0; c < 8; ++c) {
            int b = c & 1;
            f16x8 av, wv;
            if (c < 7) {
                int cn = c + 1;
                const _Float16* asrc = (cn < 4) ? Xf : Aggf;
                const _Float16* wsrc = (cn < 4) ? Wsf : Wnf;
                int kb = (cn & 3) * 32;
                av = *(const f16x8*)(asrc + (size_t)rstage * D + kb + q * 8);
                wv = *(const f16x8*)(wsrc + (size_t)r * D + kb + q * 8);
            }
            f16x8 af[2], bf[4];
            af[0] = *(const f16x8*)(&s_a[b][a_off]);
            af[1] = *(const f16x8*)(&s_a[b][a_off + 16 * LDA]);
            #pragma unroll
            for (int j = 0; j < 4; ++j) bf[j] = *(const f16x8*)(&s_b[b][b_off + j * 16 * LDA]);
            #pragma unroll
            for (int i = 0; i < 2; ++i)
                #pragma unroll
                for (int j = 0; j < 4; ++j)
                    acc[i][j] = __builtin_amdgcn_mfma_f32_16x16x32_f16(af[i], bf[j], acc[i][j], 0, 0, 0);
            if (c < 7) {
                *(f16x8*)(&s_a[b ^ 1][st_off]) = av;
                *(f16x8*)(&s_b[b ^ 1][st_off]) = wv;
            }
            __syncthreads();
        }

        #pragma unroll
        for (int j = 0; j < 4; ++j) {
            int col = wc * 64 + j * 16 + l15;
            float bv = bias[col];
            #pragma unroll
            for (int i = 0; i < 2; ++i) {
                int rowb = wr * 32 + i * 16 + lk * 4;
                #pragma unroll
                for (int v = 0; v < 4; ++v)
                    s_h2[(rowb + v) * LDAGG + col] = (_Float16)(acc[i][j][v] + bv);
            }
        }
    }

    {
        int wr = w >> 2, wc = w & 3;
        _Float16* s_flat = &s_a[0][0];
        f32x4 acc2[4][4];
        #pragma unroll
        for (int i = 0; i < 4; ++i)
            #pragma unroll
            for (int j = 0; j < 4; ++j) acc2[i][j] = (f32x4){0.f, 0.f, 0.f, 0.f};

        for (int c2 = 0; c2 < 4; ++c2) {
            __syncthreads();
            #pragma unroll
            for (int e = 0; e < 2; ++e) {
                int idx = tid + e * 512;
                int o = idx >> 2, qq = idx & 3;
                *(f16x8*)(&s_flat[o * LDA + qq * 8]) =
                    *(const f16x8*)(P1cf + (size_t)o * 128 + c2 * 32 + qq * 8);
            }
            __syncthreads();
            f16x8 af[4], bf[4];
            #pragma unroll
            for (int i = 0; i < 4; ++i)
                af[i] = *(const f16x8*)(&s_h2[(wr * 64 + i * 16 + l15) * LDAGG + c2 * 32 + lk * 8]);
            #pragma unroll
            for (int j = 0; j < 4; ++j)
                bf[j] = *(const f16x8*)(&s_flat[(wc * 64 + j * 16 + l15) * LDA + lk * 8]);
            #pragma unroll
            for (int i = 0; i < 4; ++i)
                #pragma unroll
                for (int j = 0; j < 4; ++j)
                    acc2[i][j] = __builtin_amdgcn_mfma_f32_16x16x32_f16(af[i], bf[j], acc2[i][j], 0, 0, 0);
        }

        #pragma unroll
        for (int j = 0; j < 4; ++j) {
            int col = wc * 64 + j * 16 + l15;
            #pragma unroll
            for (int i = 0; i < 4; ++i) {
                int rowb = n0 + wr * 64 + i * 16 + lk * 4;
                #pragma unroll
                for (int v = 0; v < 4; ++v) {
                    int row = rowb + v;
                    if (row < n_rows)
                        Pre[(size_t)row * 256 + col] = (_Float16)acc2[i][j][v];
                }
            }
        }
    }
}

// ---------------- fused predictor: gather Pre rows -> h1 -> P2 -> P3 ----------------
__global__ __launch_bounds__(256) void k_mlp(
    const _Float16* __restrict__ Pre,
    const int* __restrict__ pos_src, const int* __restrict__ pos_dst,
    const int* __restrict__ neg_src, const int* __restrict__ neg_dst,
    const float* __restrict__ P1b,
    const _Float16* __restrict__ P2wf, const float* __restrict__ P2b,
    const float* __restrict__ P3w, const float* __restrict__ P3b,
    float* __restrict__ out, int EP) {
    __shared__ _Float16 s_h1[64 * LDH2];
    __shared__ _Float16 s_b[2][128 * LDA];
    __shared__ float s_red[64 * 2];
    __shared__ int s_node[128];
    int tid = threadIdx.x;
    int w = tid >> 6, l = tid & 63;
    int wr = w >> 1, wc = w & 1;
    int l15 = l & 15, lk = l >> 4;
    int p0 = blockIdx.x * 64;
    int twoEP = 2 * EP;

    if (tid < 128) {
        int p = p0 + (tid & 63);
        if (p >= twoEP) p = twoEP - 1;
        int node;
        if (tid < 64) node = (p < EP) ? pos_src[p] : neg_src[p - EP];
        else          node = (p < EP) ? pos_dst[p] : neg_dst[p - EP];
        s_node[tid] = node;
    }
    __syncthreads();

    #pragma unroll
    for (int e = 0; e < 4; ++e) {
        int idx = tid + e * 256;
        int pr = idx >> 4, u = idx & 15;
        int sn = s_node[pr], dn = s_node[64 + pr];
        f16x8 a = *(const f16x8*)(Pre + (size_t)sn * 256 + u * 8);
        f16x8 b = *(const f16x8*)(Pre + (size_t)dn * 256 + 128 + u * 8);
        float4 b0 = *(const float4*)(P1b + u * 8);
        float4 b1 = *(const float4*)(P1b + u * 8 + 4);
        float bb[8] = {b0.x, b0.y, b0.z, b0.w, b1.x, b1.y, b1.z, b1.w};
        f16x8 h;
        #pragma unroll
        for (int j = 0; j < 8; ++j)
            h[j] = (_Float16)fmaxf((float)a[j] + (float)b[j] + bb[j], 0.f);
        *(f16x8*)(&s_h1[pr * LDH2 + u * 8]) = h;
    }
    #pragma unroll
    for (int e = 0; e < 2; ++e) {
        int idx = tid + e * 256;
        int o = idx >> 2, q = idx & 3;
        *(f16x8*)(&s_b[0][o * LDA + q * 8]) = *(const f16x8*)(P2wf + (size_t)o * D + q * 8);
    }
    __syncthreads();

    f32x4 acc2[2][4];
    #pragma unroll
    for (int i = 0; i < 2; ++i)
        #pragma unroll
        for (int j = 0; j < 4; ++j) acc2[i][j] = (f32x4){0.f, 0.f, 0.f, 0.f};

    for (int c = 0; c < 4; ++c) {
        int b = c & 1;
        f16x8 nw[2];
        if (c < 3) {
            #pragma unroll
            for (int e = 0; e < 2; ++e) {
                int idx = tid + e * 256;
                int o = idx >> 2, q = idx & 3;
                nw[e] = *(const f16x8*)(P2wf + (size_t)o * D + (c + 1) * 32 + q * 8);
            }
        }
        f16x8 af[2], bf[4];
        af[0] = *(const f16x8*)(&s_h1[(wr * 32 + l15) * LDH2 + c * 32 + lk * 8]);
        af[1] = *(const f16x8*)(&s_h1[(wr * 32 + 16 + l15) * LDH2 + c * 32 + lk * 8]);
        #pragma unroll
        for (int j = 0; j < 4; ++j)
            bf[j] = *(const f16x8*)(&s_b[b][(wc * 64 + j * 16 + l15) * LDA + lk * 8]);
        #pragma unroll
        for (int i = 0; i < 2; ++i)
            #pragma unroll
            for (int j = 0; j < 4; ++j)
                acc2[i][j] = __builtin_amdgcn_mfma_f32_16x16x32_f16(af[i], bf[j], acc2[i][j], 0, 0, 0);
        if (c < 3) {
            #pragma unroll
            for (int e = 0; e < 2; ++e) {
                int idx = tid + e * 256;
                int o = idx >> 2, q = idx & 3;
                *(f16x8*)(&s_b[b ^ 1][o * LDA + q * 8]) = nw[e];
            }
        }
        __syncthreads();
    }

    float b2v[4], pw[4];
    #pragma unroll
    for (int j = 0; j < 4; ++j) {
        int col = wc * 64 + j * 16 + l15;
        b2v[j] = P2b[col];
        pw[j] = P3w[col];
    }
    #pragma unroll
    for (int i = 0; i < 2; ++i) {
        #pragma unroll
        for (int v = 0; v < 4; ++v) {
            float s = 0.f;
            #pragma unroll
            for (int j = 0; j < 4; ++j)
                s += fmaxf(acc2[i][j][v] + b2v[j], 0.f) * pw[j];
            s += __shfl_xor(s, 1);
            s += __shfl_xor(s, 2);
            s += __shfl_xor(s, 4);
            s += __shfl_xor(s, 8);
            if (l15 == 0)
                s_red[(wr * 32 + i * 16 + lk * 4 + v) * 2 + wc] = s;
        }
    }
    __syncthreads();
    if (tid < 64) {
        int p = p0 + tid;
        if (p < twoEP) out[p] = s_red[tid * 2] + s_red[tid * 2 + 1] + P3b[0];
    }
}

static inline size_t align_up(size_t x, size_t a) { return (x + a - 1) & ~(a - 1); }

extern "C" void kernel_launch(void* const* d_in, const int* in_sizes, int n_in,
                              void* d_out, int out_size, void* d_ws, size_t ws_size,
                              hipStream_t stream) {
    const float* x        = (const float*)d_in[0];
    const int*   edge_src = (const int*)d_in[1];
    const int*   edge_dst = (const int*)d_in[2];
    const int*   pos_src  = (const int*)d_in[3];
    const int*   pos_dst  = (const int*)d_in[4];
    const int*   neg_src  = (const int*)d_in[5];
    const int*   neg_dst  = (const int*)d_in[6];
    const float* W1n = (const float*)d_in[7];
    const float* W1s = (const float*)d_in[8];
    const float* b1  = (const float*)d_in[9];
    const float* W2n = (const float*)d_in[10];
    const float* W2s = (const float*)d_in[11];
    const float* b2  = (const float*)d_in[12];
    const float* P1w = (const float*)d_in[13];
    const float* P1b = (const float*)d_in[14];
    const float* P2w = (const float*)d_in[15];
    const float* P2b = (const float*)d_in[16];
    const float* P3w = (const float*)d_in[17];
    const float* P3b = (const float*)d_in[18];
    float* out = (float*)d_out;

    int N = in_sizes[0] / D;
    int E = in_sizes[1];
    int EP = in_sizes[3];
    int bound = (N + NR - 1) / NR;   // nodes per region (196 < 256)

    char* ws = (char*)d_ws;
    size_t off = 0;
    int* row_off = (int*)(ws + off); off = align_up(off + (size_t)(N + 1) * 4, 256);
    int* regmeta = (int*)(ws + off); off = align_up(off + (size_t)(2 * NR) * 4, 256);
    int* csr     = (int*)(ws + off); off = align_up(off + (size_t)E * 4, 256);
    unsigned int* epart = (unsigned int*)(ws + off); off = align_up(off + (size_t)E * 4, 256);
    _Float16* xf   = (_Float16*)(ws + off); off = align_up(off + (size_t)N * D * 2, 256);
    _Float16* aggf = (_Float16*)(ws + off); off = align_up(off + (size_t)N * D * 2, 256);
    _Float16* h1f  = (_Float16*)(ws + off); off = align_up(off + (size_t)N * D * 2, 256);
    _Float16* Pre  = (_Float16*)(ws + off); off = align_up(off + (size_t)N * 256 * 2, 256);
    _Float16* Ws1f = (_Float16*)(ws + off); off = align_up(off + (size_t)D * D * 2, 256);
    _Float16* Wn1f = (_Float16*)(ws + off); off = align_up(off + (size_t)D * D * 2, 256);
    _Float16* Ws2f = (_Float16*)(ws + off); off = align_up(off + (size_t)D * D * 2, 256);
    _Float16* Wn2f = (_Float16*)(ws + off); off = align_up(off + (size_t)D * D * 2, 256);
    _Float16* P1cf = (_Float16*)(ws + off); off = align_up(off + (size_t)2 * D * D * 2, 256);
    _Float16* P2wf = (_Float16*)(ws + off); off = align_up(off + (size_t)D * D * 2, 256);
    (void)ws_size;

    int* region_cnt = regmeta;        // [NR]
    int* cursor2    = regmeta + NR;   // [NR]

    int n8 = N * D / 8;

    // --- cooperative setup + CSR build ---
    hipMemsetAsync(regmeta, 0, 2 * NR * 4, stream);
    {
        void* args[] = {
            (void*)&x, (void*)&xf, (void*)&n8,
            (void*)&W1s, (void*)&W1n, (void*)&W2s, (void*)&W2n,
            (void*)&P1w, (void*)&P2w,
            (void*)&Ws1f, (void*)&Wn1f, (void*)&Ws2f, (void*)&Wn2f,
            (void*)&P1cf, (void*)&P2wf,
            (void*)&edge_src, (void*)&edge_dst,
            (void*)&epart, (void*)&csr, (void*)&row_off,
            (void*)&region_cnt, (void*)&cursor2,
            (void*)&N, (void*)&E, (void*)&bound
        };
        hipLaunchCooperativeKernel((const void*)k_csr, dim3(NR), dim3(256),
                                   args, 0, stream);
    }

    const int ngrid = (N + 127) / 128;
    const int pgrid = (2 * EP + 63) / 64;

    // --- layer 1 ---
    k_agg<<<(N + 15) / 16, 256, 0, stream>>>(xf, row_off, csr, aggf, N);
    k_transform<<<ngrid, 512, 0, stream>>>(xf, aggf, Ws1f, Wn1f, b1, h1f, N);
    // --- layer 2 (fused with Pre GEMM) ---
    k_agg<<<(N + 15) / 16, 256, 0, stream>>>(h1f, row_off, csr, aggf, N);
    k_transform_pre<<<ngrid, 512, 0, stream>>>(h1f, aggf, Ws2f, Wn2f, b2, P1cf, Pre, N);

    // --- predictor ---
    k_mlp<<<pgrid, 256, 0, stream>>>(Pre, pos_src, pos_dst, neg_src, neg_dst,
                                     P1b, P2wf, P2b, P3w, P3b, out, EP);
}

// Round 16
// 303.336 us; speedup vs baseline: 1.3580x; 1.3580x over previous
//
#include <hip/hip_runtime.h>
#include <hip/hip_bf16.h>
#include <hip/hip_fp16.h>

// GraphSAGE(2-layer, mean agg) + 3-layer MLP link predictor.
// N=100000, E=1.6M, E_PAIR=100000, D=128.
// Round 16: revert to R14 (best: 303.6us). R15's cooperative CSR fusion
// regressed (single 512-block grid starved phase-0 streaming); split chain
// restored. k_agg is at the random-gather ceiling (3.56 TB/s, probed 3x).

#define D 128
#define NR 512
#define LDA 40       // f16 elems per staged row (80B stride: 2-way banks = free)
#define LDAGG 136    // s_h2 row stride f16
#define LDH2 136     // s_h1 row stride f16

typedef _Float16 f16x8 __attribute__((ext_vector_type(8)));
typedef float f32x4 __attribute__((ext_vector_type(4)));

__device__ __forceinline__ void cvt8(const float* src, _Float16* dst, int off8) {
    const float4* s4 = (const float4*)src;
    float4 a = s4[2 * off8], b = s4[2 * off8 + 1];
    f16x8 h;
    h[0] = (_Float16)a.x; h[1] = (_Float16)a.y; h[2] = (_Float16)a.z; h[3] = (_Float16)a.w;
    h[4] = (_Float16)b.x; h[5] = (_Float16)b.y; h[6] = (_Float16)b.z; h[7] = (_Float16)b.w;
    *(f16x8*)(dst + 8 * off8) = h;
}

// ---------------- k_setup: cvt_x | cvt_weights | region histogram ----------------
__global__ __launch_bounds__(256) void k_setup(
    const float* __restrict__ x, _Float16* __restrict__ xf, int n8, int nb_x,
    const float* __restrict__ W1s, const float* __restrict__ W1n,
    const float* __restrict__ W2s, const float* __restrict__ W2n,
    const float* __restrict__ P1w, const float* __restrict__ P2w,
    _Float16* __restrict__ Ws1f, _Float16* __restrict__ Wn1f,
    _Float16* __restrict__ Ws2f, _Float16* __restrict__ Wn2f,
    _Float16* __restrict__ P1cf, _Float16* __restrict__ P2wf,
    const int* __restrict__ dst, int* __restrict__ region_cnt, int e, int bound) {
    int b = blockIdx.x;
    if (b < nb_x) {
        int i = b * 256 + threadIdx.x;
        if (i < n8) cvt8(x, xf, i);
        return;
    }
    b -= nb_x;
    if (b < 56) {
        int g = b * 256 + threadIdx.x;
        if (g >= 14336) return;
        if (g >= 8192 && g < 12288) {
            int u = g - 8192;
            int o = u >> 4, col = (u & 15) * 8;
            const float* src = P1w + (size_t)(o & 127) * 256 + ((o >> 7) * 128) + col;
            float4 a = *(const float4*)src, bb = *(const float4*)(src + 4);
            f16x8 h;
            h[0] = (_Float16)a.x; h[1] = (_Float16)a.y; h[2] = (_Float16)a.z; h[3] = (_Float16)a.w;
            h[4] = (_Float16)bb.x; h[5] = (_Float16)bb.y; h[6] = (_Float16)bb.z; h[7] = (_Float16)bb.w;
            *(f16x8*)(P1cf + (size_t)u * 8) = h;
            return;
        }
        const float* src; _Float16* dstp; int off;
        if      (g <  2048) { src = W1s; dstp = Ws1f; off = g; }
        else if (g <  4096) { src = W1n; dstp = Wn1f; off = g - 2048; }
        else if (g <  6144) { src = W2s; dstp = Ws2f; off = g - 4096; }
        else if (g <  8192) { src = W2n; dstp = Wn2f; off = g - 6144; }
        else                { src = P2w; dstp = P2wf; off = g - 12288; }
        cvt8(src, dstp, off);
        return;
    }
    b -= 56;
    __shared__ int s[NR];
    for (int i = threadIdx.x; i < NR; i += 256) s[i] = 0;
    __syncthreads();
    for (int i = b * 256 + threadIdx.x; i < e; i += 128 * 256)
        atomicAdd(&s[dst[i] / bound], 1);
    __syncthreads();
    for (int i = threadIdx.x; i < NR; i += 256)
        if (s[i]) atomicAdd(&region_cnt[i], s[i]);
}

// ---------------- parallel exclusive scan of region counts ----------------
__global__ __launch_bounds__(NR) void k_regbase(
    const int* __restrict__ region_cnt,
    int* __restrict__ region_base, int* __restrict__ region_cursor) {
    __shared__ int s[NR];
    int t = threadIdx.x;
    int v = region_cnt[t];
    s[t] = v;
    __syncthreads();
    #pragma unroll
    for (int off = 1; off < NR; off <<= 1) {
        int add = (t >= off) ? s[t - off] : 0;
        __syncthreads();
        s[t] += add;
        __syncthreads();
    }
    int ex = s[t] - v;
    region_base[t] = ex;
    region_cursor[t] = ex;
    if (t == NR - 1) region_base[NR] = s[t];
}

// ---------------- partition edges (per-block span reservation) ----------------
__global__ __launch_bounds__(256) void k_regpart(
    const int* __restrict__ src, const int* __restrict__ dst,
    unsigned int* __restrict__ eout, int* __restrict__ region_cursor, int e, int bound) {
    __shared__ int s_cnt[NR];
    __shared__ int s_base[NR];
    int per = (e + gridDim.x - 1) / gridDim.x;
    int beg = blockIdx.x * per;
    int end = min(beg + per, e);
    for (int i = threadIdx.x; i < NR; i += 256) s_cnt[i] = 0;
    __syncthreads();
    for (int i = beg + threadIdx.x; i < end; i += 256)
        atomicAdd(&s_cnt[dst[i] / bound], 1);
    __syncthreads();
    for (int i = threadIdx.x; i < NR; i += 256)
        s_base[i] = s_cnt[i] ? atomicAdd(&region_cursor[i], s_cnt[i]) : 0;
    __syncthreads();
    for (int i = threadIdx.x; i < NR; i += 256) s_cnt[i] = 0;
    __syncthreads();
    for (int i = beg + threadIdx.x; i < end; i += 256) {
        int d = dst[i];
        int r = d / bound;
        unsigned int doff = (unsigned int)(d - r * bound);
        int p = atomicAdd(&s_cnt[r], 1);
        eout[s_base[r] + p] = (unsigned int)src[i] | (doff << 20);
    }
}

// ---------------- fused per-region rowoff + scatter ----------------
#define EMAX 4608
__global__ __launch_bounds__(256) void k_rowoff_scatter(
    const unsigned int* __restrict__ ep, const int* __restrict__ region_base,
    int* __restrict__ row_off, int* __restrict__ csr, int n, int bound) {
    int r = blockIdx.x;
    int rlo = r * bound;
    if (threadIdx.x == 0 && r == 0) row_off[n] = region_base[NR];
    if (rlo >= n) return;
    int nn = min(bound, n - rlo);
    __shared__ unsigned int s_e[EMAX];
    __shared__ int s_deg[256];
    __shared__ int s_scan[256];
    __shared__ int s_cur[256];
    int beg = region_base[r], end = region_base[r + 1];
    int cnt = end - beg;
    bool fit = (cnt <= EMAX);
    if (fit)
        for (int i = threadIdx.x; i < cnt; i += 256) s_e[i] = ep[beg + i];
    s_deg[threadIdx.x] = 0;
    __syncthreads();
    for (int i = threadIdx.x; i < cnt; i += 256)
        atomicAdd(&s_deg[(fit ? s_e[i] : ep[beg + i]) >> 20], 1);
    __syncthreads();
    int v = (threadIdx.x < nn) ? s_deg[threadIdx.x] : 0;
    s_scan[threadIdx.x] = v;
    __syncthreads();
    #pragma unroll
    for (int off = 1; off < 256; off <<= 1) {
        int add = (threadIdx.x >= off) ? s_scan[threadIdx.x - off] : 0;
        __syncthreads();
        s_scan[threadIdx.x] += add;
        __syncthreads();
    }
    int base = beg + (threadIdx.x ? s_scan[threadIdx.x - 1] : 0);
    s_cur[threadIdx.x] = base;
    if (threadIdx.x < nn) row_off[rlo + threadIdx.x] = base;
    __syncthreads();
    for (int i = threadIdx.x; i < cnt; i += 256) {
        unsigned int e2 = fit ? s_e[i] : ep[beg + i];
        int doff = e2 >> 20;
        int p = atomicAdd(&s_cur[doff], 1);
        csr[p] = e2 & 0xFFFFF;
    }
}

// ---------------- mean aggregation: 16-lane group per node ----------------
__global__ __launch_bounds__(256) void k_agg(
    const _Float16* __restrict__ Xf, const int* __restrict__ row_off,
    const int* __restrict__ csr, _Float16* __restrict__ Aggf, int n_nodes) {
    int g = blockIdx.x * 16 + (threadIdx.x >> 4);
    if (g >= n_nodes) return;
    int l = threadIdx.x & 15;
    int beg = row_off[g], end = row_off[g + 1];
    float acc[8] = {0.f, 0.f, 0.f, 0.f, 0.f, 0.f, 0.f, 0.f};
    int i = beg;
    for (; i + 8 <= end; i += 8) {
        int si[8];
        #pragma unroll
        for (int j = 0; j < 8; ++j) si[j] = csr[i + j];
        f16x8 vv[8];
        #pragma unroll
        for (int j = 0; j < 8; ++j)
            vv[j] = *(const f16x8*)(Xf + (size_t)si[j] * D + l * 8);
        #pragma unroll
        for (int j = 0; j < 8; ++j)
            #pragma unroll
            for (int k = 0; k < 8; ++k) acc[k] += (float)vv[j][k];
    }
    for (; i + 2 <= end; i += 2) {
        int s0 = csr[i], s1 = csr[i + 1];
        f16x8 v0 = *(const f16x8*)(Xf + (size_t)s0 * D + l * 8);
        f16x8 v1 = *(const f16x8*)(Xf + (size_t)s1 * D + l * 8);
        #pragma unroll
        for (int k = 0; k < 8; ++k) acc[k] += (float)v0[k] + (float)v1[k];
    }
    if (i < end) {
        int s0 = csr[i];
        f16x8 v0 = *(const f16x8*)(Xf + (size_t)s0 * D + l * 8);
        #pragma unroll
        for (int k = 0; k < 8; ++k) acc[k] += (float)v0[k];
    }
    float inv = 1.0f / fmaxf((float)(end - beg), 1.0f);
    f16x8 o;
    #pragma unroll
    for (int k = 0; k < 8; ++k) o[k] = (_Float16)(acc[k] * inv);
    *(f16x8*)(Aggf + (size_t)g * D + l * 8) = o;
}

// ---------------- layer-1 transform (MFMA, double-buffered, relu) ----------------
__global__ __launch_bounds__(512) void k_transform(
    const _Float16* __restrict__ Xf, const _Float16* __restrict__ Aggf,
    const _Float16* __restrict__ Wsf, const _Float16* __restrict__ Wnf,
    const float* __restrict__ bias, _Float16* __restrict__ outf, int n_rows) {
    __shared__ _Float16 s_a[2][128 * LDA];
    __shared__ _Float16 s_b[2][128 * LDA];
    int tid = threadIdx.x;
    int w = tid >> 6, l = tid & 63;
    int wr = w >> 1, wc = w & 1;
    int l15 = l & 15, lk = l >> 4;
    int n0 = blockIdx.x * 128;
    int r = tid >> 2, q = tid & 3;
    int rstage = n0 + r; if (rstage >= n_rows) rstage = n_rows - 1;

    f32x4 acc[2][4];
    #pragma unroll
    for (int i = 0; i < 2; ++i)
        #pragma unroll
        for (int j = 0; j < 4; ++j) acc[i][j] = (f32x4){0.f, 0.f, 0.f, 0.f};

    int a_off = (wr * 32 + l15) * LDA + lk * 8;
    int b_off = (wc * 64 + l15) * LDA + lk * 8;
    int st_off = r * LDA + q * 8;

    {
        f16x8 av = *(const f16x8*)(Xf + (size_t)rstage * D + q * 8);
        f16x8 wv = *(const f16x8*)(Wsf + (size_t)r * D + q * 8);
        *(f16x8*)(&s_a[0][st_off]) = av;
        *(f16x8*)(&s_b[0][st_off]) = wv;
    }
    __syncthreads();

    for (int c = 0; c < 8; ++c) {
        int b = c & 1;
        f16x8 av, wv;
        if (c < 7) {
            int cn = c + 1;
            const _Float16* asrc = (cn < 4) ? Xf : Aggf;
            const _Float16* wsrc = (cn < 4) ? Wsf : Wnf;
            int kb = (cn & 3) * 32;
            av = *(const f16x8*)(asrc + (size_t)rstage * D + kb + q * 8);
            wv = *(const f16x8*)(wsrc + (size_t)r * D + kb + q * 8);
        }
        f16x8 af[2], bf[4];
        af[0] = *(const f16x8*)(&s_a[b][a_off]);
        af[1] = *(const f16x8*)(&s_a[b][a_off + 16 * LDA]);
        #pragma unroll
        for (int j = 0; j < 4; ++j) bf[j] = *(const f16x8*)(&s_b[b][b_off + j * 16 * LDA]);
        #pragma unroll
        for (int i = 0; i < 2; ++i)
            #pragma unroll
            for (int j = 0; j < 4; ++j)
                acc[i][j] = __builtin_amdgcn_mfma_f32_16x16x32_f16(af[i], bf[j], acc[i][j], 0, 0, 0);
        if (c < 7) {
            *(f16x8*)(&s_a[b ^ 1][st_off]) = av;
            *(f16x8*)(&s_b[b ^ 1][st_off]) = wv;
        }
        __syncthreads();
    }

    #pragma unroll
    for (int j = 0; j < 4; ++j) {
        int col = wc * 64 + j * 16 + l15;
        float bv = bias[col];
        #pragma unroll
        for (int i = 0; i < 2; ++i) {
            int rowb = n0 + wr * 32 + i * 16 + lk * 4;
            #pragma unroll
            for (int v = 0; v < 4; ++v) {
                int row = rowb + v;
                if (row < n_rows)
                    outf[(size_t)row * D + col] = (_Float16)fmaxf(acc[i][j][v] + bv, 0.f);
            }
        }
    }
}

// ---------------- layer-2 transform fused with Pre GEMM ----------------
__global__ __launch_bounds__(512) void k_transform_pre(
    const _Float16* __restrict__ Xf, const _Float16* __restrict__ Aggf,
    const _Float16* __restrict__ Wsf, const _Float16* __restrict__ Wnf,
    const float* __restrict__ bias, const _Float16* __restrict__ P1cf,
    _Float16* __restrict__ Pre, int n_rows) {
    __shared__ _Float16 s_a[2][128 * LDA];
    __shared__ _Float16 s_b[2][128 * LDA];
    __shared__ _Float16 s_h2[128 * LDAGG];
    int tid = threadIdx.x;
    int w = tid >> 6, l = tid & 63;
    int l15 = l & 15, lk = l >> 4;
    int n0 = blockIdx.x * 128;
    int r = tid >> 2, q = tid & 3;
    int rstage = n0 + r; if (rstage >= n_rows) rstage = n_rows - 1;

    {
        int wr = w >> 1, wc = w & 1;
        f32x4 acc[2][4];
        #pragma unroll
        for (int i = 0; i < 2; ++i)
            #pragma unroll
            for (int j = 0; j < 4; ++j) acc[i][j] = (f32x4){0.f, 0.f, 0.f, 0.f};

        int a_off = (wr * 32 + l15) * LDA + lk * 8;
        int b_off = (wc * 64 + l15) * LDA + lk * 8;
        int st_off = r * LDA + q * 8;

        f16x8 av0 = *(const f16x8*)(Xf + (size_t)rstage * D + q * 8);
        f16x8 wv0 = *(const f16x8*)(Wsf + (size_t)r * D + q * 8);
        *(f16x8*)(&s_a[0][st_off]) = av0;
        *(f16x8*)(&s_b[0][st_off]) = wv0;
        __syncthreads();

        for (int c = 0; c < 8; ++c) {
            int b = c & 1;
            f16x8 av, wv;
            if (c < 7) {
                int cn = c + 1;
                const _Float16* asrc = (cn < 4) ? Xf : Aggf;
                const _Float16* wsrc = (cn < 4) ? Wsf : Wnf;
                int kb = (cn & 3) * 32;
                av = *(const f16x8*)(asrc + (size_t)rstage * D + kb + q * 8);
                wv = *(const f16x8*)(wsrc + (size_t)r * D + kb + q * 8);
            }
            f16x8 af[2], bf[4];
            af[0] = *(const f16x8*)(&s_a[b][a_off]);
            af[1] = *(const f16x8*)(&s_a[b][a_off + 16 * LDA]);
            #pragma unroll
            for (int j = 0; j < 4; ++j) bf[j] = *(const f16x8*)(&s_b[b][b_off + j * 16 * LDA]);
            #pragma unroll
            for (int i = 0; i < 2; ++i)
                #pragma unroll
                for (int j = 0; j < 4; ++j)
                    acc[i][j] = __builtin_amdgcn_mfma_f32_16x16x32_f16(af[i], bf[j], acc[i][j], 0, 0, 0);
            if (c < 7) {
                *(f16x8*)(&s_a[b ^ 1][st_off]) = av;
                *(f16x8*)(&s_b[b ^ 1][st_off]) = wv;
            }
            __syncthreads();
        }

        #pragma unroll
        for (int j = 0; j < 4; ++j) {
            int col = wc * 64 + j * 16 + l15;
            float bv = bias[col];
            #pragma unroll
            for (int i = 0; i < 2; ++i) {
                int rowb = wr * 32 + i * 16 + lk * 4;
                #pragma unroll
                for (int v = 0; v < 4; ++v)
                    s_h2[(rowb + v) * LDAGG + col] = (_Float16)(acc[i][j][v] + bv);
            }
        }
    }

    {
        int wr = w >> 2, wc = w & 3;
        _Float16* s_flat = &s_a[0][0];
        f32x4 acc2[4][4];
        #pragma unroll
        for (int i = 0; i < 4; ++i)
            #pragma unroll
            for (int j = 0; j < 4; ++j) acc2[i][j] = (f32x4){0.f, 0.f, 0.f, 0.f};

        for (int c2 = 0; c2 < 4; ++c2) {
            __syncthreads();
            #pragma unroll
            for (int e = 0; e < 2; ++e) {
                int idx = tid + e * 512;
                int o = idx >> 2, qq = idx & 3;
                *(f16x8*)(&s_flat[o * LDA + qq * 8]) =
                    *(const f16x8*)(P1cf + (size_t)o * 128 + c2 * 32 + qq * 8);
            }
            __syncthreads();
            f16x8 af[4], bf[4];
            #pragma unroll
            for (int i = 0; i < 4; ++i)
                af[i] = *(const f16x8*)(&s_h2[(wr * 64 + i * 16 + l15) * LDAGG + c2 * 32 + lk * 8]);
            #pragma unroll
            for (int j = 0; j < 4; ++j)
                bf[j] = *(const f16x8*)(&s_flat[(wc * 64 + j * 16 + l15) * LDA + lk * 8]);
            #pragma unroll
            for (int i = 0; i < 4; ++i)
                #pragma unroll
                for (int j = 0; j < 4; ++j)
                    acc2[i][j] = __builtin_amdgcn_mfma_f32_16x16x32_f16(af[i], bf[j], acc2[i][j], 0, 0, 0);
        }

        #pragma unroll
        for (int j = 0; j < 4; ++j) {
            int col = wc * 64 + j * 16 + l15;
            #pragma unroll
            for (int i = 0; i < 4; ++i) {
                int rowb = n0 + wr * 64 + i * 16 + lk * 4;
                #pragma unroll
                for (int v = 0; v < 4; ++v) {
                    int row = rowb + v;
                    if (row < n_rows)
                        Pre[(size_t)row * 256 + col] = (_Float16)acc2[i][j][v];
                }
            }
        }
    }
}

// ---------------- fused predictor: gather Pre rows -> h1 -> P2 -> P3 ----------------
__global__ __launch_bounds__(256) void k_mlp(
    const _Float16* __restrict__ Pre,
    const int* __restrict__ pos_src, const int* __restrict__ pos_dst,
    const int* __restrict__ neg_src, const int* __restrict__ neg_dst,
    const float* __restrict__ P1b,
    const _Float16* __restrict__ P2wf, const float* __restrict__ P2b,
    const float* __restrict__ P3w, const float* __restrict__ P3b,
    float* __restrict__ out, int EP) {
    __shared__ _Float16 s_h1[64 * LDH2];
    __shared__ _Float16 s_b[2][128 * LDA];
    __shared__ float s_red[64 * 2];
    __shared__ int s_node[128];
    int tid = threadIdx.x;
    int w = tid >> 6, l = tid & 63;
    int wr = w >> 1, wc = w & 1;
    int l15 = l & 15, lk = l >> 4;
    int p0 = blockIdx.x * 64;
    int twoEP = 2 * EP;

    if (tid < 128) {
        int p = p0 + (tid & 63);
        if (p >= twoEP) p = twoEP - 1;
        int node;
        if (tid < 64) node = (p < EP) ? pos_src[p] : neg_src[p - EP];
        else          node = (p < EP) ? pos_dst[p] : neg_dst[p - EP];
        s_node[tid] = node;
    }
    __syncthreads();

    #pragma unroll
    for (int e = 0; e < 4; ++e) {
        int idx = tid + e * 256;
        int pr = idx >> 4, u = idx & 15;
        int sn = s_node[pr], dn = s_node[64 + pr];
        f16x8 a = *(const f16x8*)(Pre + (size_t)sn * 256 + u * 8);
        f16x8 b = *(const f16x8*)(Pre + (size_t)dn * 256 + 128 + u * 8);
        float4 b0 = *(const float4*)(P1b + u * 8);
        float4 b1 = *(const float4*)(P1b + u * 8 + 4);
        float bb[8] = {b0.x, b0.y, b0.z, b0.w, b1.x, b1.y, b1.z, b1.w};
        f16x8 h;
        #pragma unroll
        for (int j = 0; j < 8; ++j)
            h[j] = (_Float16)fmaxf((float)a[j] + (float)b[j] + bb[j], 0.f);
        *(f16x8*)(&s_h1[pr * LDH2 + u * 8]) = h;
    }
    #pragma unroll
    for (int e = 0; e < 2; ++e) {
        int idx = tid + e * 256;
        int o = idx >> 2, q = idx & 3;
        *(f16x8*)(&s_b[0][o * LDA + q * 8]) = *(const f16x8*)(P2wf + (size_t)o * D + q * 8);
    }
    __syncthreads();

    f32x4 acc2[2][4];
    #pragma unroll
    for (int i = 0; i < 2; ++i)
        #pragma unroll
        for (int j = 0; j < 4; ++j) acc2[i][j] = (f32x4){0.f, 0.f, 0.f, 0.f};

    for (int c = 0; c < 4; ++c) {
        int b = c & 1;
        f16x8 nw[2];
        if (c < 3) {
            #pragma unroll
            for (int e = 0; e < 2; ++e) {
                int idx = tid + e * 256;
                int o = idx >> 2, q = idx & 3;
                nw[e] = *(const f16x8*)(P2wf + (size_t)o * D + (c + 1) * 32 + q * 8);
            }
        }
        f16x8 af[2], bf[4];
        af[0] = *(const f16x8*)(&s_h1[(wr * 32 + l15) * LDH2 + c * 32 + lk * 8]);
        af[1] = *(const f16x8*)(&s_h1[(wr * 32 + 16 + l15) * LDH2 + c * 32 + lk * 8]);
        #pragma unroll
        for (int j = 0; j < 4; ++j)
            bf[j] = *(const f16x8*)(&s_b[b][(wc * 64 + j * 16 + l15) * LDA + lk * 8]);
        #pragma unroll
        for (int i = 0; i < 2; ++i)
            #pragma unroll
            for (int j = 0; j < 4; ++j)
                acc2[i][j] = __builtin_amdgcn_mfma_f32_16x16x32_f16(af[i], bf[j], acc2[i][j], 0, 0, 0);
        if (c < 3) {
            #pragma unroll
            for (int e = 0; e < 2; ++e) {
                int idx = tid + e * 256;
                int o = idx >> 2, q = idx & 3;
                *(f16x8*)(&s_b[b ^ 1][o * LDA + q * 8]) = nw[e];
            }
        }
        __syncthreads();
    }

    float b2v[4], pw[4];
    #pragma unroll
    for (int j = 0; j < 4; ++j) {
        int col = wc * 64 + j * 16 + l15;
        b2v[j] = P2b[col];
        pw[j] = P3w[col];
    }
    #pragma unroll
    for (int i = 0; i < 2; ++i) {
        #pragma unroll
        for (int v = 0; v < 4; ++v) {
            float s = 0.f;
            #pragma unroll
            for (int j = 0; j < 4; ++j)
                s += fmaxf(acc2[i][j][v] + b2v[j], 0.f) * pw[j];
            s += __shfl_xor(s, 1);
            s += __shfl_xor(s, 2);
            s += __shfl_xor(s, 4);
            s += __shfl_xor(s, 8);
            if (l15 == 0)
                s_red[(wr * 32 + i * 16 + lk * 4 + v) * 2 + wc] = s;
        }
    }
    __syncthreads();
    if (tid < 64) {
        int p = p0 + tid;
        if (p < twoEP) out[p] = s_red[tid * 2] + s_red[tid * 2 + 1] + P3b[0];
    }
}

static inline size_t align_up(size_t x, size_t a) { return (x + a - 1) & ~(a - 1); }

extern "C" void kernel_launch(void* const* d_in, const int* in_sizes, int n_in,
                              void* d_out, int out_size, void* d_ws, size_t ws_size,
                              hipStream_t stream) {
    const float* x        = (const float*)d_in[0];
    const int*   edge_src = (const int*)d_in[1];
    const int*   edge_dst = (const int*)d_in[2];
    const int*   pos_src  = (const int*)d_in[3];
    const int*   pos_dst  = (const int*)d_in[4];
    const int*   neg_src  = (const int*)d_in[5];
    const int*   neg_dst  = (const int*)d_in[6];
    const float* W1n = (const float*)d_in[7];
    const float* W1s = (const float*)d_in[8];
    const float* b1  = (const float*)d_in[9];
    const float* W2n = (const float*)d_in[10];
    const float* W2s = (const float*)d_in[11];
    const float* b2  = (const float*)d_in[12];
    const float* P1w = (const float*)d_in[13];
    const float* P1b = (const float*)d_in[14];
    const float* P2w = (const float*)d_in[15];
    const float* P2b = (const float*)d_in[16];
    const float* P3w = (const float*)d_in[17];
    const float* P3b = (const float*)d_in[18];
    float* out = (float*)d_out;

    const int N = in_sizes[0] / D;
    const int E = in_sizes[1];
    const int EP = in_sizes[3];
    const int bound = (N + NR - 1) / NR;   // nodes per region (196 < 256)

    char* ws = (char*)d_ws;
    size_t off = 0;
    int* row_off = (int*)(ws + off); off = align_up(off + (size_t)(N + 1) * 4, 256);
    int* regmeta = (int*)(ws + off); off = align_up(off + (size_t)(3 * NR + 8) * 4, 256);
    int* csr     = (int*)(ws + off); off = align_up(off + (size_t)E * 4, 256);
    unsigned int* epart = (unsigned int*)(ws + off); off = align_up(off + (size_t)E * 4, 256);
    _Float16* xf   = (_Float16*)(ws + off); off = align_up(off + (size_t)N * D * 2, 256);
    _Float16* aggf = (_Float16*)(ws + off); off = align_up(off + (size_t)N * D * 2, 256);
    _Float16* h1f  = (_Float16*)(ws + off); off = align_up(off + (size_t)N * D * 2, 256);
    _Float16* Pre  = (_Float16*)(ws + off); off = align_up(off + (size_t)N * 256 * 2, 256);
    _Float16* Ws1f = (_Float16*)(ws + off); off = align_up(off + (size_t)D * D * 2, 256);
    _Float16* Wn1f = (_Float16*)(ws + off); off = align_up(off + (size_t)D * D * 2, 256);
    _Float16* Ws2f = (_Float16*)(ws + off); off = align_up(off + (size_t)D * D * 2, 256);
    _Float16* Wn2f = (_Float16*)(ws + off); off = align_up(off + (size_t)D * D * 2, 256);
    _Float16* P1cf = (_Float16*)(ws + off); off = align_up(off + (size_t)2 * D * D * 2, 256);
    _Float16* P2wf = (_Float16*)(ws + off); off = align_up(off + (size_t)D * D * 2, 256);
    (void)ws_size;

    int* region_cnt    = regmeta;               // [NR]
    int* region_base   = regmeta + NR;          // [NR+1]
    int* region_cursor = regmeta + 2 * NR + 4;  // [NR]

    const int n8 = N * D / 8;
    const int nb_x = (n8 + 255) / 256;

    // --- setup: cvt_x + cvt_weights + region histogram (one launch) ---
    hipMemsetAsync(region_cnt, 0, NR * 4, stream);
    k_setup<<<nb_x + 56 + 128, 256, 0, stream>>>(
        x, xf, n8, nb_x, W1s, W1n, W2s, W2n, P1w, P2w,
        Ws1f, Wn1f, Ws2f, Wn2f, P1cf, P2wf,
        edge_dst, region_cnt, E, bound);
    k_regbase<<<1, NR, 0, stream>>>(region_cnt, region_base, region_cursor);
    k_regpart<<<128, 256, 0, stream>>>(edge_src, edge_dst, epart, region_cursor, E, bound);
    k_rowoff_scatter<<<NR, 256, 0, stream>>>(epart, region_base, row_off, csr, N, bound);

    const int ngrid = (N + 127) / 128;
    const int pgrid = (2 * EP + 63) / 64;

    // --- layer 1 ---
    k_agg<<<(N + 15) / 16, 256, 0, stream>>>(xf, row_off, csr, aggf, N);
    k_transform<<<ngrid, 512, 0, stream>>>(xf, aggf, Ws1f, Wn1f, b1, h1f, N);
    // --- layer 2 (fused with Pre GEMM; h2 never globalized) ---
    k_agg<<<(N + 15) / 16, 256, 0, stream>>>(h1f, row_off, csr, aggf, N);
    k_transform_pre<<<ngrid, 512, 0, stream>>>(h1f, aggf, Ws2f, Wn2f, b2, P1cf, Pre, N);

    // --- predictor ---
    k_mlp<<<pgrid, 256, 0, stream>>>(Pre, pos_src, pos_dst, neg_src, neg_dst,
                                     P1b, P2wf, P2b, P3w, P3b, out, EP);
}